// Round 2
// baseline (154.264 us; speedup 1.0000x reference)
//
#include <hip/hip_runtime.h>
#include <stdint.h>

#define KK 5
#define SCALE_F 50000.0f
#define OC 128
#define IC 128
#define HH 56
#define WW 56
#define NB 64
#define HWSZ (HH * WW)          // 3136
#define NTAP 9
#define NWEL (OC * IC * NTAP)   // 147456
#define OCPT 16                 // output channels per thread in bconv

// ---------------------------------------------------------------------------
// Kernel 1: SDP stochastic weight generation + binarize + bit-pack.
// One wave (64 lanes) per (oc, tap, word); lane l -> ic = word*64 + l.
// ---------------------------------------------------------------------------
__global__ void __launch_bounds__(256) wpack_kernel(
    const float* __restrict__ M, const float* __restrict__ Z,
    const float* __restrict__ rv, uint64_t* __restrict__ wpk) {
    int gtid = blockIdx.x * blockDim.x + threadIdx.x;
    int lane = gtid & 63;
    int wid  = gtid >> 6;            // 0..2303
    int oc   = wid / 18;
    int r    = wid - oc * 18;
    int tap  = r >> 1;
    int word = r & 1;
    int ic   = word * 64 + lane;
    int idx  = (oc * IC + ic) * NTAP + tap;

    float m  = M[idx];
    float z0 = Z[0 * NWEL + idx];
    float z1 = Z[1 * NWEL + idx];
    float z2 = Z[2 * NWEL + idx];
    float z3 = Z[3 * NWEL + idx];
    float z4 = Z[4 * NWEL + idx];
    float s  = z0 * z0 + z1 * z1 + z2 * z2 + z3 * z3 + z4 * z4;
    float A  = m * m + s * (1.0f / SCALE_F);
    float inv = 1.0f / sqrtf(A);
    float w = rv[0] * (z0 * inv);
    w += rv[1] * (z1 * inv);
    w += rv[2] * (z2 * inv);
    w += rv[3] * (z3 * inv);
    w += rv[4] * (z4 * inv);
    w += m * inv;

    unsigned long long b = __ballot(w > 0.0f);
    if (lane == 0) wpk[(oc * NTAP + tap) * 2 + word] = b;
}

// ---------------------------------------------------------------------------
// Kernel 2: binarize + bit-pack activations. One thread per (n, hw, word);
// each thread packs 64 channels into one u64. apk layout: [n][hw][2] u64.
// 401408 threads -> 1568 blocks (2x the old occupancy).
// ---------------------------------------------------------------------------
__global__ void __launch_bounds__(256) apack_kernel(
    const float* __restrict__ x, uint64_t* __restrict__ apk) {
    int q    = blockIdx.x * blockDim.x + threadIdx.x;  // 0..401407
    int word = q & 1;
    int p    = q >> 1;                                 // 0..200703
    int n    = p / HWSZ;
    int hw   = p - n * HWSZ;
    const float* xp = x + (size_t)n * IC * HWSZ + (size_t)word * 64 * HWSZ + hw;

    uint64_t b = 0;
#pragma unroll
    for (int c = 0; c < 64; ++c)
        b |= (uint64_t)(xp[(size_t)c * HWSZ] > 0.0f) << c;

    apk[(size_t)p * 2 + word] = b;
}

// ---------------------------------------------------------------------------
// Kernel 3: XNOR-popcount conv 3x3 pad 1 + alpha scale.
// grid = (784, 8): blockIdx.x -> spatial chunk (one thread per (n,h,w)),
// blockIdx.y -> group of OCPT=16 output channels. 6272 blocks total.
// Weights indexed only by loop vars / blockIdx -> wave-uniform s_loads.
// Interior pixels (93%) take a select-free fast path.
// ---------------------------------------------------------------------------
__global__ void __launch_bounds__(256) bconv_kernel(
    const uint64_t* __restrict__ apk, const uint64_t* __restrict__ wpk,
    const float* __restrict__ alpha, float* __restrict__ out) {
    int p  = blockIdx.x * blockDim.x + threadIdx.x;   // 0..200703
    int n  = p / HWSZ;
    int hw = p - n * HWSZ;
    int h  = hw / WW;
    int w  = hw - h * WW;
    int oc0 = blockIdx.y * OCPT;

    uint64_t alo[NTAP], ahi[NTAP];
    unsigned validm = 0;
    const ulonglong2* ap = (const ulonglong2*)apk + (size_t)n * HWSZ;
#pragma unroll
    for (int t = 0; t < NTAP; ++t) {
        int dh = t / 3 - 1, dw = t % 3 - 1;
        int hh = h + dh, ww2 = w + dw;
        bool v = (hh >= 0) && (hh < HH) && (ww2 >= 0) && (ww2 < WW);
        int addr = v ? (hh * WW + ww2) : hw;   // clamp invalid to self (unused)
        ulonglong2 a = ap[addr];
        alo[t] = a.x;
        ahi[t] = a.y;
        validm |= (unsigned)v << t;
    }

    const ulonglong2* wq = (const ulonglong2*)wpk + oc0 * NTAP;
    float* op = out + (size_t)n * OC * HWSZ + (size_t)oc0 * HWSZ + hw;

    if (validm == 0x1FFu) {
        // interior: all 9 taps valid, no per-tap select
#pragma unroll 4
        for (int oc = 0; oc < OCPT; ++oc) {
            int cnt = 0;
#pragma unroll
            for (int t = 0; t < NTAP; ++t) {
                ulonglong2 wv = wq[oc * NTAP + t];    // uniform -> s_load
                cnt += __popcll(alo[t] ^ wv.x) + __popcll(ahi[t] ^ wv.y);
            }
            op[(size_t)oc * HWSZ] = (float)(NTAP * 128 - 2 * cnt) * alpha[oc0 + oc];
        }
    } else {
        // border: invalid tap contributes 0 => substitute popc 64
#pragma unroll 4
        for (int oc = 0; oc < OCPT; ++oc) {
            int cnt = 0;
#pragma unroll
            for (int t = 0; t < NTAP; ++t) {
                ulonglong2 wv = wq[oc * NTAP + t];
                int pc = __popcll(alo[t] ^ wv.x) + __popcll(ahi[t] ^ wv.y);
                cnt += ((validm >> t) & 1) ? pc : 64;
            }
            op[(size_t)oc * HWSZ] = (float)(NTAP * 128 - 2 * cnt) * alpha[oc0 + oc];
        }
    }
}

extern "C" void kernel_launch(void* const* d_in, const int* in_sizes, int n_in,
                              void* d_out, int out_size, void* d_ws, size_t ws_size,
                              hipStream_t stream) {
    const float* x     = (const float*)d_in[0];
    const float* M     = (const float*)d_in[1];
    const float* Z     = (const float*)d_in[2];
    const float* Alpha = (const float*)d_in[3];
    const float* rv    = (const float*)d_in[4];
    float* out = (float*)d_out;

    uint64_t* wpk = (uint64_t*)d_ws;
    uint64_t* apk = (uint64_t*)((char*)d_ws + 32768);

    wpack_kernel<<<NWEL / 256, 256, 0, stream>>>(M, Z, rv, wpk);
    apack_kernel<<<(NB * HWSZ * 2) / 256, 256, 0, stream>>>(x, apk);
    bconv_kernel<<<dim3((NB * HWSZ) / 256, OC / OCPT), 256, 0, stream>>>(
        apk, wpk, Alpha, out);
}

// Round 3
// 143.947 us; speedup vs baseline: 1.0717x; 1.0717x over previous
//
#include <hip/hip_runtime.h>
#include <stdint.h>

#define KK 5
#define SCALE_F 50000.0f
#define OC 128
#define IC 128
#define HH 56
#define WW 56
#define NB 64
#define HWSZ (HH * WW)          // 3136
#define NTAP 9
#define NWEL (OC * IC * NTAP)   // 147456
#define PH 58                   // padded spatial dim
#define PHW (PH * PH)           // 3364
#define OCPB 8                  // oc per block (grid.y = 16)
#define WPT 4                   // outputs along w per thread

// ---------------------------------------------------------------------------
// Kernel 1: SDP stochastic weight generation + binarize + bit-pack.
// One wave per (oc, tap, word); lane l -> ic = word*64 + l.
// wpk layout: [oc][tap] as ulonglong2 (lo=ic 0..63, hi=ic 64..127).
// ---------------------------------------------------------------------------
__global__ void __launch_bounds__(256) wpack_kernel(
    const float* __restrict__ M, const float* __restrict__ Z,
    const float* __restrict__ rv, uint64_t* __restrict__ wpk) {
    int gtid = blockIdx.x * blockDim.x + threadIdx.x;
    int lane = gtid & 63;
    int wid  = gtid >> 6;            // 0..2303
    int oc   = wid / 18;
    int r    = wid - oc * 18;
    int tap  = r >> 1;
    int word = r & 1;
    int ic   = word * 64 + lane;
    int idx  = (oc * IC + ic) * NTAP + tap;

    float m  = M[idx];
    float z0 = Z[0 * NWEL + idx];
    float z1 = Z[1 * NWEL + idx];
    float z2 = Z[2 * NWEL + idx];
    float z3 = Z[3 * NWEL + idx];
    float z4 = Z[4 * NWEL + idx];
    float s  = z0 * z0 + z1 * z1 + z2 * z2 + z3 * z3 + z4 * z4;
    float A  = m * m + s * (1.0f / SCALE_F);
    float inv = 1.0f / sqrtf(A);
    float w = rv[0] * (z0 * inv);
    w += rv[1] * (z1 * inv);
    w += rv[2] * (z2 * inv);
    w += rv[3] * (z3 * inv);
    w += rv[4] * (z4 * inv);
    w += m * inv;

    unsigned long long b = __ballot(w > 0.0f);
    if (lane == 0) wpk[(oc * NTAP + tap) * 2 + word] = b;
}

// ---------------------------------------------------------------------------
// Kernel 2: binarize + bit-pack activations into ZERO-PADDED buffer.
// apk layout: [n][58][58] ulonglong2; borders pre-zeroed by memset.
// One thread per (n, hw, word).
// ---------------------------------------------------------------------------
__global__ void __launch_bounds__(256) apack_kernel(
    const float* __restrict__ x, uint64_t* __restrict__ apk) {
    int q    = blockIdx.x * blockDim.x + threadIdx.x;  // 0..401407
    int word = q & 1;
    int p    = q >> 1;                                 // 0..200703
    int n    = p / HWSZ;
    int hw   = p - n * HWSZ;
    int h    = hw / WW;
    int w    = hw - h * WW;
    const float* xp = x + (size_t)n * IC * HWSZ + (size_t)word * 64 * HWSZ + hw;

    uint64_t b = 0;
#pragma unroll
    for (int c = 0; c < 64; ++c)
        b |= (uint64_t)(xp[(size_t)c * HWSZ] > 0.0f) << c;

    size_t dst = ((size_t)n * PHW + (size_t)(h + 1) * PH + (w + 1)) * 2 + word;
    apk[dst] = b;
}

// ---------------------------------------------------------------------------
// Kernel 3: XNOR-popcount conv. grid = (196, 16).
// Thread -> (n, h, 4-wide w strip); block handles OCPB=8 output channels.
// Loop nest: rows outer, oc INNER with persistent accumulators cnt[4][8]
// (computed values -> cannot be rematerialized; taps loaded once, die fast).
// Weights + border-correction table + alpha staged in LDS.
// ---------------------------------------------------------------------------
__global__ void __launch_bounds__(256) bconv_kernel(
    const uint64_t* __restrict__ apk, const uint64_t* __restrict__ wpk,
    const float* __restrict__ alpha, float* __restrict__ out) {
    __shared__ ulonglong2 wlds[OCPB * NTAP];   // 1152 B
    __shared__ int adj[OCPB][9];               // border-class correction
    __shared__ float alf[OCPB];

    int tx  = threadIdx.x;
    int oc0 = blockIdx.y * OCPB;

    if (tx < OCPB * NTAP) wlds[tx] = ((const ulonglong2*)wpk)[oc0 * NTAP + tx];
    if (tx < OCPB)        alf[tx]  = alpha[oc0 + tx];
    __syncthreads();

    if (tx < OCPB * 9) {
        int ocl = tx / 9, cls = tx % 9;
        int rc = cls / 3, cc = cls % 3;
        int nv = ((rc == 1) ? 3 : 2) * ((cc == 1) ? 3 : 2);
        int s = 0;
#pragma unroll
        for (int t = 0; t < NTAP; ++t) {
            int i = t / 3, j = t % 3;
            bool invld = (rc == 0 && i == 0) || (rc == 2 && i == 2) ||
                         (cc == 0 && j == 0) || (cc == 2 && j == 2);
            if (invld) {
                ulonglong2 wv = wlds[ocl * NTAP + t];
                s += __popcll(wv.x) + __popcll(wv.y);
            }
        }
        adj[ocl][cls] = 128 * nv + 2 * s;
    }
    __syncthreads();

    int t  = blockIdx.x * blockDim.x + tx;     // 0..50175
    int sw = t % 14;
    int h  = (t / 14) % HH;
    int n  = t / (14 * HH);
    int w0 = sw * WPT;

    // padded tap base: rows h..h+2, cols w0..w0+5
    const ulonglong2* ap = (const ulonglong2*)apk + (size_t)n * PHW + (size_t)h * PH + w0;

    int cnt[WPT * OCPB] = {0};                 // 32 VGPR accumulators
#pragma unroll
    for (int r = 0; r < 3; ++r) {
        ulonglong2 R0 = ap[(size_t)r * PH + 0];
        ulonglong2 R1 = ap[(size_t)r * PH + 1];
        ulonglong2 R2 = ap[(size_t)r * PH + 2];
        ulonglong2 R3 = ap[(size_t)r * PH + 3];
        ulonglong2 R4 = ap[(size_t)r * PH + 4];
        ulonglong2 R5 = ap[(size_t)r * PH + 5];
        ulonglong2 R[6] = {R0, R1, R2, R3, R4, R5};
#pragma unroll
        for (int j = 0; j < 3; ++j) {
#pragma unroll
            for (int ocl = 0; ocl < OCPB; ++ocl) {
                ulonglong2 wv = wlds[ocl * NTAP + r * 3 + j];
#pragma unroll
                for (int o = 0; o < WPT; ++o) {
                    cnt[o * OCPB + ocl] += __popcll(R[j + o].x ^ wv.x) +
                                           __popcll(R[j + o].y ^ wv.y);
                }
            }
        }
    }

    int rcls = (h == 0) ? 0 : ((h == HH - 1) ? 6 : 3);
    float* op = out + ((size_t)n * OC + oc0) * HWSZ + h * WW + w0;
#pragma unroll
    for (int ocl = 0; ocl < OCPB; ++ocl) {
        float4 v;
        {
            int cls = rcls + ((w0 + 0 == 0) ? 0 : ((w0 + 0 == WW - 1) ? 2 : 1));
            v.x = (float)(adj[ocl][cls] - 2 * cnt[0 * OCPB + ocl]) * alf[ocl];
        }
        {
            int cls = rcls + 1;  // w0+1,2 in [1,54] always interior cols
            v.y = (float)(adj[ocl][cls] - 2 * cnt[1 * OCPB + ocl]) * alf[ocl];
            v.z = (float)(adj[ocl][cls] - 2 * cnt[2 * OCPB + ocl]) * alf[ocl];
        }
        {
            int cls = rcls + ((w0 + 3 == WW - 1) ? 2 : 1);
            v.w = (float)(adj[ocl][cls] - 2 * cnt[3 * OCPB + ocl]) * alf[ocl];
        }
        *(float4*)(op + (size_t)ocl * HWSZ) = v;
    }
}

extern "C" void kernel_launch(void* const* d_in, const int* in_sizes, int n_in,
                              void* d_out, int out_size, void* d_ws, size_t ws_size,
                              hipStream_t stream) {
    const float* x     = (const float*)d_in[0];
    const float* M     = (const float*)d_in[1];
    const float* Z     = (const float*)d_in[2];
    const float* Alpha = (const float*)d_in[3];
    const float* rv    = (const float*)d_in[4];
    float* out = (float*)d_out;

    uint64_t* wpk = (uint64_t*)d_ws;                          // 18,432 B
    uint64_t* apk = (uint64_t*)((char*)d_ws + 32768);         // 64*3364*16 B

    // zero the padded activation buffer (borders must be 0 every call)
    hipMemsetAsync(apk, 0, (size_t)NB * PHW * 16, stream);

    wpack_kernel<<<NWEL / 256, 256, 0, stream>>>(M, Z, rv, wpk);
    apack_kernel<<<(NB * HWSZ * 2) / 256, 256, 0, stream>>>(x, apk);
    bconv_kernel<<<dim3((NB * HH * 14) / 256, OC / OCPB), 256, 0, stream>>>(
        apk, wpk, Alpha, out);
}

// Round 4
// 119.025 us; speedup vs baseline: 1.2961x; 1.2094x over previous
//
#include <hip/hip_runtime.h>
#include <stdint.h>

#define KK 5
#define SCALE_F 50000.0f
#define OC 128
#define IC 128
#define HH 56
#define WW 56
#define NB 64
#define HWSZ (HH * WW)          // 3136
#define NTAP 9
#define NWEL (OC * IC * NTAP)   // 147456
#define PH 58                   // padded spatial dim
#define PHW (PH * PH)           // 3364
#define OCPB 2                  // oc per block (grid.y = 64)
#define WPT 8                   // outputs along w per thread (56 = 7 * 8)

// ---------------------------------------------------------------------------
// Kernel 1: SDP stochastic weight generation + binarize + bit-pack.
// One wave per (oc, tap, word); lane l -> ic = word*64 + l.
// wpk layout: [oc][tap] as ulonglong2 (lo=ic 0..63, hi=ic 64..127).
// ---------------------------------------------------------------------------
__global__ void __launch_bounds__(256) wpack_kernel(
    const float* __restrict__ M, const float* __restrict__ Z,
    const float* __restrict__ rv, uint64_t* __restrict__ wpk) {
    int gtid = blockIdx.x * blockDim.x + threadIdx.x;
    int lane = gtid & 63;
    int wid  = gtid >> 6;            // 0..2303
    int oc   = wid / 18;
    int r    = wid - oc * 18;
    int tap  = r >> 1;
    int word = r & 1;
    int ic   = word * 64 + lane;
    int idx  = (oc * IC + ic) * NTAP + tap;

    float m  = M[idx];
    float z0 = Z[0 * NWEL + idx];
    float z1 = Z[1 * NWEL + idx];
    float z2 = Z[2 * NWEL + idx];
    float z3 = Z[3 * NWEL + idx];
    float z4 = Z[4 * NWEL + idx];
    float s  = z0 * z0 + z1 * z1 + z2 * z2 + z3 * z3 + z4 * z4;
    float A  = m * m + s * (1.0f / SCALE_F);
    float inv = 1.0f / sqrtf(A);
    float w = rv[0] * (z0 * inv);
    w += rv[1] * (z1 * inv);
    w += rv[2] * (z2 * inv);
    w += rv[3] * (z3 * inv);
    w += rv[4] * (z4 * inv);
    w += m * inv;

    unsigned long long b = __ballot(w > 0.0f);
    if (lane == 0) wpk[(oc * NTAP + tap) * 2 + word] = b;
}

// ---------------------------------------------------------------------------
// Kernel 2: binarize + bit-pack activations into ZERO-PADDED buffer.
// apk layout: [n][58][58] ulonglong2; borders pre-zeroed by memset.
// ---------------------------------------------------------------------------
__global__ void __launch_bounds__(256) apack_kernel(
    const float* __restrict__ x, uint64_t* __restrict__ apk) {
    int q    = blockIdx.x * blockDim.x + threadIdx.x;  // 0..401407
    int word = q & 1;
    int p    = q >> 1;                                 // 0..200703
    int n    = p / HWSZ;
    int hw   = p - n * HWSZ;
    int h    = hw / WW;
    int w    = hw - h * WW;
    const float* xp = x + (size_t)n * IC * HWSZ + (size_t)word * 64 * HWSZ + hw;

    uint64_t b = 0;
#pragma unroll
    for (int c = 0; c < 64; ++c)
        b |= (uint64_t)(xp[(size_t)c * HWSZ] > 0.0f) << c;

    size_t dst = ((size_t)n * PHW + (size_t)(h + 1) * PH + (w + 1)) * 2 + word;
    apk[dst] = b;
}

// ---------------------------------------------------------------------------
// Kernel 3: XNOR-popcount conv. grid = (98, 64), 256 threads.
// Thread -> (n, h, 8-wide w strip) x OCPB=2 output channels.
// Row loop kept rolled (#pragma unroll 1) so only one row of taps (10
// ulonglong2 = 20 VGPR) is live at a time -> high occupancy.
// Weights (18 ulonglong2) + border-adjust table + alpha staged in LDS.
// ---------------------------------------------------------------------------
__global__ void __launch_bounds__(256, 4) bconv_kernel(
    const uint64_t* __restrict__ apk, const uint64_t* __restrict__ wpk,
    const float* __restrict__ alpha, float* __restrict__ out) {
    __shared__ ulonglong2 wlds[NTAP * OCPB];   // [tap][ocl], 288 B
    __shared__ int adj[OCPB][9];               // border-class correction
    __shared__ float alf[OCPB];

    int tx  = threadIdx.x;
    int oc0 = blockIdx.y * OCPB;

    if (tx < NTAP * OCPB) {
        int tap = tx >> 1, ocl = tx & 1;
        wlds[tap * OCPB + ocl] = ((const ulonglong2*)wpk)[(oc0 + ocl) * NTAP + tap];
    }
    if (tx < OCPB) alf[tx] = alpha[oc0 + tx];
    __syncthreads();

    if (tx < OCPB * 9) {
        int ocl = tx / 9, cls = tx % 9;
        int rc = cls / 3, cc = cls % 3;
        int nv = ((rc == 1) ? 3 : 2) * ((cc == 1) ? 3 : 2);
        int s = 0;
#pragma unroll
        for (int t = 0; t < NTAP; ++t) {
            int i = t / 3, j = t % 3;
            bool invld = (rc == 0 && i == 0) || (rc == 2 && i == 2) ||
                         (cc == 0 && j == 0) || (cc == 2 && j == 2);
            if (invld) {
                ulonglong2 wv = wlds[t * OCPB + ocl];
                s += __popcll(wv.x) + __popcll(wv.y);
            }
        }
        adj[ocl][cls] = 128 * nv + 2 * s;
    }
    __syncthreads();

    int t  = blockIdx.x * blockDim.x + tx;     // 0..25087
    int sw = t % 7;
    int h  = (t / 7) % HH;
    int n  = t / (7 * HH);
    int w0 = sw * WPT;

    // padded tap base: rows h..h+2 (unpadded h-1..h+1), cols w0..w0+9
    const ulonglong2* ap = (const ulonglong2*)apk + (size_t)n * PHW + (size_t)h * PH + w0;

    int cnt[WPT * OCPB] = {0};                 // 16 accumulators
#pragma unroll 1
    for (int r = 0; r < 3; ++r) {
        ulonglong2 T[10];
#pragma unroll
        for (int c = 0; c < 10; ++c) T[c] = ap[(size_t)r * PH + c];
#pragma unroll
        for (int j = 0; j < 3; ++j) {
#pragma unroll
            for (int ocl = 0; ocl < OCPB; ++ocl) {
                ulonglong2 wv = wlds[(r * 3 + j) * OCPB + ocl];
#pragma unroll
                for (int o = 0; o < WPT; ++o) {
                    cnt[o * OCPB + ocl] += __popcll(T[j + o].x ^ wv.x) +
                                           __popcll(T[j + o].y ^ wv.y);
                }
            }
        }
    }

    int rcls = (h == 0) ? 0 : ((h == HH - 1) ? 6 : 3);
    float* op = out + ((size_t)n * OC + oc0) * HWSZ + h * WW + w0;
#pragma unroll
    for (int ocl = 0; ocl < OCPB; ++ocl) {
        float a = alf[ocl];
        int cA = adj[ocl][rcls + ((w0 == 0) ? 0 : 1)];        // col 0 of strip
        int cI = adj[ocl][rcls + 1];                          // interior cols
        int cB = adj[ocl][rcls + ((w0 == WW - WPT) ? 2 : 1)]; // col 7 of strip
        float4 v0, v1;
        v0.x = (float)(cA - 2 * cnt[0 * OCPB + ocl]) * a;
        v0.y = (float)(cI - 2 * cnt[1 * OCPB + ocl]) * a;
        v0.z = (float)(cI - 2 * cnt[2 * OCPB + ocl]) * a;
        v0.w = (float)(cI - 2 * cnt[3 * OCPB + ocl]) * a;
        v1.x = (float)(cI - 2 * cnt[4 * OCPB + ocl]) * a;
        v1.y = (float)(cI - 2 * cnt[5 * OCPB + ocl]) * a;
        v1.z = (float)(cI - 2 * cnt[6 * OCPB + ocl]) * a;
        v1.w = (float)(cB - 2 * cnt[7 * OCPB + ocl]) * a;
        *(float4*)(op + (size_t)ocl * HWSZ)     = v0;
        *(float4*)(op + (size_t)ocl * HWSZ + 4) = v1;
    }
}

extern "C" void kernel_launch(void* const* d_in, const int* in_sizes, int n_in,
                              void* d_out, int out_size, void* d_ws, size_t ws_size,
                              hipStream_t stream) {
    const float* x     = (const float*)d_in[0];
    const float* M     = (const float*)d_in[1];
    const float* Z     = (const float*)d_in[2];
    const float* Alpha = (const float*)d_in[3];
    const float* rv    = (const float*)d_in[4];
    float* out = (float*)d_out;

    uint64_t* wpk = (uint64_t*)d_ws;                          // 18,432 B
    uint64_t* apk = (uint64_t*)((char*)d_ws + 32768);         // 64*3364*16 B

    // zero the padded activation buffer (borders must be 0 every call)
    hipMemsetAsync(apk, 0, (size_t)NB * PHW * 16, stream);

    wpack_kernel<<<NWEL / 256, 256, 0, stream>>>(M, Z, rv, wpk);
    apack_kernel<<<(NB * HWSZ * 2) / 256, 256, 0, stream>>>(x, apk);
    bconv_kernel<<<dim3((NB * HH * 7) / 256, OC / OCPB), 256, 0, stream>>>(
        apk, wpk, Alpha, out);
}

// Round 5
// 92.987 us; speedup vs baseline: 1.6590x; 1.2800x over previous
//
#include <hip/hip_runtime.h>
#include <stdint.h>

#define KK 5
#define SCALE_F 50000.0f
#define OC 128
#define IC 128
#define HH 56
#define WW 56
#define NB 64
#define HWSZ (HH * WW)          // 3136
#define NTAP 9
#define NWEL (OC * IC * NTAP)   // 147456
#define PW 60                   // padded row stride (u32), 240 B = 16B-aligned
#define PROWS 58                // padded rows
#define PLANE (PROWS * PW)      // 3480 u32 per (plane, n)
#define PLSTRIDE (NB * PLANE)   // 222720 u32 per plane
#define OCPB 2                  // oc per block (grid.y = 64)
#define WPT 4                   // outputs along w per thread (56 = 14 * 4)

// ---------------------------------------------------------------------------
// Kernel 1: SDP stochastic weight generation + binarize + bit-pack.
// One wave per (oc, tap, word64); lane l -> ic = word64*64 + l.
// wpk layout: [oc][tap] as 2x u64 (lo=ic 0..63, hi=ic 64..127); as u32[4]:
// word wd holds ic wd*32..wd*32+31 -- matches activation plane wd.
// ---------------------------------------------------------------------------
__global__ void __launch_bounds__(256) wpack_kernel(
    const float* __restrict__ M, const float* __restrict__ Z,
    const float* __restrict__ rv, uint64_t* __restrict__ wpk) {
    int gtid = blockIdx.x * blockDim.x + threadIdx.x;
    int lane = gtid & 63;
    int wid  = gtid >> 6;            // 0..2303
    int oc   = wid / 18;
    int r    = wid - oc * 18;
    int tap  = r >> 1;
    int word = r & 1;
    int ic   = word * 64 + lane;
    int idx  = (oc * IC + ic) * NTAP + tap;

    float m  = M[idx];
    float z0 = Z[0 * NWEL + idx];
    float z1 = Z[1 * NWEL + idx];
    float z2 = Z[2 * NWEL + idx];
    float z3 = Z[3 * NWEL + idx];
    float z4 = Z[4 * NWEL + idx];
    float s  = z0 * z0 + z1 * z1 + z2 * z2 + z3 * z3 + z4 * z4;
    float A  = m * m + s * (1.0f / SCALE_F);
    float inv = 1.0f / sqrtf(A);
    float w = rv[0] * (z0 * inv);
    w += rv[1] * (z1 * inv);
    w += rv[2] * (z2 * inv);
    w += rv[3] * (z3 * inv);
    w += rv[4] * (z4 * inv);
    w += m * inv;

    unsigned long long b = __ballot(w > 0.0f);
    if (lane == 0) wpk[(oc * NTAP + tap) * 2 + word] = b;
}

// ---------------------------------------------------------------------------
// Kernel 2: binarize + pack activations into 4 ZERO-PADDED u32 planes.
// Plane wd holds ic wd*32..wd*32+31. grid = (784, 4); blockIdx.y = plane.
// Consecutive threads -> consecutive pixels -> fully coalesced reads.
// ---------------------------------------------------------------------------
__global__ void __launch_bounds__(256) apack_kernel(
    const float* __restrict__ x, uint32_t* __restrict__ apk32) {
    int q  = blockIdx.x * blockDim.x + threadIdx.x;   // 0..200703
    int wd = blockIdx.y;                              // 0..3
    int n  = q / HWSZ;
    int hw = q - n * HWSZ;
    int h  = hw / WW;
    int w  = hw - h * WW;
    const float* xp = x + (size_t)n * IC * HWSZ + (size_t)wd * 32 * HWSZ + hw;

    uint32_t b = 0;
#pragma unroll
    for (int c = 0; c < 32; ++c)
        b |= (uint32_t)(xp[(size_t)c * HWSZ] > 0.0f) << c;

    apk32[(size_t)wd * PLSTRIDE + (size_t)n * PLANE + (size_t)(h + 1) * PW + (w + 1)] = b;
}

// ---------------------------------------------------------------------------
// Kernel 3: XNOR-popcount conv. grid = (196, 64), 256 threads.
// Thread -> (n, h, 4-wide w strip) x OCPB=2 output channels.
// Rolled (r, wd) loops keep live state tiny: T[6] u32 taps + cnt[8]
// accumulators (~32 VGPR -> high occupancy). Weights read per use from
// global via wave-uniform address -> scalar s_load (no VALU/LDS cost).
// Border correction via tiny LDS adj table (padding taps read 0 bits).
// ---------------------------------------------------------------------------
__global__ void __launch_bounds__(256, 8) bconv_kernel(
    const uint32_t* __restrict__ apk32, const uint64_t* __restrict__ wpk,
    const float* __restrict__ alpha, float* __restrict__ out) {
    __shared__ int adj[OCPB][9];               // border-class correction
    __shared__ float alf[OCPB];

    int tx  = threadIdx.x;
    int oc0 = blockIdx.y * OCPB;

    if (tx < OCPB) alf[tx] = alpha[oc0 + tx];
    if (tx < OCPB * 9) {
        int ocl = tx / 9, cls = tx % 9;
        int rc = cls / 3, cc = cls % 3;
        int nv = ((rc == 1) ? 3 : 2) * ((cc == 1) ? 3 : 2);
        int s = 0;
#pragma unroll
        for (int t = 0; t < NTAP; ++t) {
            int i = t / 3, j = t % 3;
            bool invld = (rc == 0 && i == 0) || (rc == 2 && i == 2) ||
                         (cc == 0 && j == 0) || (cc == 2 && j == 2);
            if (invld) {
                ulonglong2 wv = ((const ulonglong2*)wpk)[(oc0 + ocl) * NTAP + t];
                s += __popcll(wv.x) + __popcll(wv.y);
            }
        }
        adj[ocl][cls] = 128 * nv + 2 * s;
    }
    __syncthreads();

    int t  = blockIdx.x * blockDim.x + tx;     // 0..50175
    int sw = t % 14;
    int h  = (t / 14) % HH;
    int n  = t / (14 * HH);
    int w0 = sw * WPT;                         // 0,4,...,52

    // padded base: rows h..h+2, cols w0..w0+5 (16B-aligned: w0 % 4 == 0)
    const uint32_t* ap = apk32 + (size_t)n * PLANE + (size_t)h * PW + w0;
    const uint32_t* wp = (const uint32_t*)wpk + oc0 * (NTAP * 4);

    int cnt[WPT * OCPB] = {0};                 // 8 accumulators
#pragma unroll 1
    for (int r = 0; r < 3; ++r) {
#pragma unroll 1
        for (int wd = 0; wd < 4; ++wd) {
            const uint32_t* p = ap + (size_t)wd * PLSTRIDE + (size_t)r * PW;
            uint32_t T[6];
#pragma unroll
            for (int c = 0; c < 6; ++c) T[c] = p[c];
#pragma unroll
            for (int j = 0; j < 3; ++j) {
#pragma unroll
                for (int ocl = 0; ocl < OCPB; ++ocl) {
                    uint32_t wv = wp[(ocl * NTAP + r * 3 + j) * 4 + wd]; // s_load
#pragma unroll
                    for (int o = 0; o < WPT; ++o)
                        cnt[o * OCPB + ocl] += __popc(T[j + o] ^ wv);
                }
            }
        }
    }

    int rcls = (h == 0) ? 0 : ((h == HH - 1) ? 6 : 3);
    int clsL = rcls + ((w0 == 0) ? 0 : 1);
    int clsI = rcls + 1;
    int clsR = rcls + ((w0 == WW - WPT) ? 2 : 1);
    float* op = out + ((size_t)n * OC + oc0) * HWSZ + h * WW + w0;
#pragma unroll
    for (int ocl = 0; ocl < OCPB; ++ocl) {
        float a = alf[ocl];
        float4 v;
        v.x = (float)(adj[ocl][clsL] - 2 * cnt[0 * OCPB + ocl]) * a;
        v.y = (float)(adj[ocl][clsI] - 2 * cnt[1 * OCPB + ocl]) * a;
        v.z = (float)(adj[ocl][clsI] - 2 * cnt[2 * OCPB + ocl]) * a;
        v.w = (float)(adj[ocl][clsR] - 2 * cnt[3 * OCPB + ocl]) * a;
        *(float4*)(op + (size_t)ocl * HWSZ) = v;
    }
}

extern "C" void kernel_launch(void* const* d_in, const int* in_sizes, int n_in,
                              void* d_out, int out_size, void* d_ws, size_t ws_size,
                              hipStream_t stream) {
    const float* x     = (const float*)d_in[0];
    const float* M     = (const float*)d_in[1];
    const float* Z     = (const float*)d_in[2];
    const float* Alpha = (const float*)d_in[3];
    const float* rv    = (const float*)d_in[4];
    float* out = (float*)d_out;

    uint64_t* wpk   = (uint64_t*)d_ws;                        // 18,432 B
    uint32_t* apk32 = (uint32_t*)((char*)d_ws + 32768);       // 4*222720*4 B

    // zero the padded activation planes (borders must be 0 every call)
    hipMemsetAsync(apk32, 0, (size_t)4 * PLSTRIDE * 4, stream);

    wpack_kernel<<<NWEL / 256, 256, 0, stream>>>(M, Z, rv, wpk);
    apack_kernel<<<dim3((NB * HWSZ) / 256, 4), 256, 0, stream>>>(x, apk32);
    bconv_kernel<<<dim3((NB * HH * 14) / 256, OC / OCPB), 256, 0, stream>>>(
        apk32, wpk, Alpha, out);
}